// Round 3
// baseline (1038.856 us; speedup 1.0000x reference)
//
#include <hip/hip_runtime.h>

// Problem constants
#define B_   64
#define T_   512
#define F_   512
#define F2_  256
#define F4_  128
#define R_   32768      // B*T slots
#define RM_  131072     // R*4 move rows

// ---------------------------------------------------------------------------
// Fused 2-layer MLP: out[r][0:128] = relu(A[r][0:K] @ W1[K][256] + b1) @ W2[256][128] + b2
// 32 rows per block, 256 threads. All fp32.
// ---------------------------------------------------------------------------
template<int KDIM>
__global__ __launch_bounds__(256, 3)
void mlp2_kernel(const float* __restrict__ A,
                 const float* __restrict__ W1, const float* __restrict__ b1,
                 const float* __restrict__ W2, const float* __restrict__ b2,
                 float* __restrict__ out)
{
    __shared__ float H[32][260];   // relu intermediate, padded
    __shared__ float As[32][20];   // A chunk 32 x 16, padded
    __shared__ float Bs[4096];     // stage1: [16][256] W1 chunk; stage2: [32][128] W2 chunk

    const int tid  = threadIdx.x;
    const int row0 = blockIdx.x * 32;
    const int tx   = tid & 31;
    const int ty   = tid >> 5;

    // ---------------- stage 1: H = relu(A_tile @ W1 + b1) ----------------
    float acc[4][8];
#pragma unroll
    for (int i = 0; i < 4; i++)
#pragma unroll
        for (int j = 0; j < 8; j++) acc[i][j] = 0.f;

    for (int k0 = 0; k0 < KDIM; k0 += 16) {
        {   // A chunk: 32 rows x 16 k
            int r = tid >> 3;
            int c = (tid & 7) * 2;
            float2 v = *(const float2*)&A[(size_t)(row0 + r) * KDIM + k0 + c];
            *(float2*)&As[r][c] = v;
        }
        {   // W1 chunk: 16 k x 256 n
            int kk = tid >> 4;
            int c0 = (tid & 15) * 16;
            const float* src = &W1[(size_t)(k0 + kk) * F2_ + c0];
            float* dst = &Bs[kk * F2_ + c0];
#pragma unroll
            for (int j = 0; j < 4; j++) ((float4*)dst)[j] = ((const float4*)src)[j];
        }
        __syncthreads();
#pragma unroll
        for (int kk = 0; kk < 16; kk += 4) {
            float4 a[4];
#pragma unroll
            for (int i = 0; i < 4; i++) a[i] = *(const float4*)&As[ty * 4 + i][kk];
#pragma unroll
            for (int u = 0; u < 4; u++) {
                float4 w0 = *(const float4*)&Bs[(kk + u) * F2_ + tx * 8];
                float4 w1 = *(const float4*)&Bs[(kk + u) * F2_ + tx * 8 + 4];
#pragma unroll
                for (int i = 0; i < 4; i++) {
                    float av = ((const float*)&a[i])[u];
                    acc[i][0] += av * w0.x; acc[i][1] += av * w0.y;
                    acc[i][2] += av * w0.z; acc[i][3] += av * w0.w;
                    acc[i][4] += av * w1.x; acc[i][5] += av * w1.y;
                    acc[i][6] += av * w1.z; acc[i][7] += av * w1.w;
                }
            }
        }
        __syncthreads();
    }
    {   // bias + relu -> H
        float4 b1a = *(const float4*)&b1[tx * 8];
        float4 b1b = *(const float4*)&b1[tx * 8 + 4];
        const float bv[8] = {b1a.x, b1a.y, b1a.z, b1a.w, b1b.x, b1b.y, b1b.z, b1b.w};
#pragma unroll
        for (int i = 0; i < 4; i++) {
            float4 h0, h1;
            h0.x = fmaxf(acc[i][0] + bv[0], 0.f);
            h0.y = fmaxf(acc[i][1] + bv[1], 0.f);
            h0.z = fmaxf(acc[i][2] + bv[2], 0.f);
            h0.w = fmaxf(acc[i][3] + bv[3], 0.f);
            h1.x = fmaxf(acc[i][4] + bv[4], 0.f);
            h1.y = fmaxf(acc[i][5] + bv[5], 0.f);
            h1.z = fmaxf(acc[i][6] + bv[6], 0.f);
            h1.w = fmaxf(acc[i][7] + bv[7], 0.f);
            *(float4*)&H[ty * 4 + i][tx * 8]     = h0;
            *(float4*)&H[ty * 4 + i][tx * 8 + 4] = h1;
        }
    }
    __syncthreads();

    // ---------------- stage 2: out = H @ W2 + b2 ----------------
    float acc2[4][4];
#pragma unroll
    for (int i = 0; i < 4; i++)
#pragma unroll
        for (int j = 0; j < 4; j++) acc2[i][j] = 0.f;

    for (int k0 = 0; k0 < F2_; k0 += 32) {
        {   // W2 chunk: 32 k x 128 n
            int kk = tid >> 3;
            int c0 = (tid & 7) * 16;
            const float* src = &W2[(size_t)(k0 + kk) * F4_ + c0];
            float* dst = &Bs[kk * F4_ + c0];
#pragma unroll
            for (int j = 0; j < 4; j++) ((float4*)dst)[j] = ((const float4*)src)[j];
        }
        __syncthreads();
#pragma unroll
        for (int kk = 0; kk < 32; kk += 4) {
            float4 h[4];
#pragma unroll
            for (int i = 0; i < 4; i++) h[i] = *(const float4*)&H[ty * 4 + i][k0 + kk];
#pragma unroll
            for (int u = 0; u < 4; u++) {
                float4 w = *(const float4*)&Bs[(kk + u) * F4_ + tx * 4];
#pragma unroll
                for (int i = 0; i < 4; i++) {
                    float hv = ((const float*)&h[i])[u];
                    acc2[i][0] += hv * w.x; acc2[i][1] += hv * w.y;
                    acc2[i][2] += hv * w.z; acc2[i][3] += hv * w.w;
                }
            }
        }
        __syncthreads();
    }
    {
        float4 bb = *(const float4*)&b2[tx * 4];
#pragma unroll
        for (int i = 0; i < 4; i++) {
            float4 o;
            o.x = acc2[i][0] + bb.x;
            o.y = acc2[i][1] + bb.y;
            o.z = acc2[i][2] + bb.z;
            o.w = acc2[i][3] + bb.w;
            *(float4*)&out[(size_t)(row0 + ty * 4 + i) * F4_ + tx * 4] = o;
        }
    }
}

// ---------------------------------------------------------------------------
// JAX threefry2x32 with key (0, 42)
// ---------------------------------------------------------------------------
__device__ __forceinline__ void threefry2x32_k42(unsigned int& x0, unsigned int& x1)
{
    const unsigned int ks0 = 0u;
    const unsigned int ks1 = 42u;
    const unsigned int ks2 = 0x1BD11BDAu ^ 42u;
    x0 += ks0; x1 += ks1;
#define TFR(r) { x0 += x1; x1 = (x1 << (r)) | (x1 >> (32 - (r))); x1 ^= x0; }
    TFR(13) TFR(15) TFR(26) TFR(6)
    x0 += ks1; x1 += ks2 + 1u;
    TFR(17) TFR(29) TFR(16) TFR(24)
    x0 += ks2; x1 += ks0 + 2u;
    TFR(13) TFR(15) TFR(26) TFR(6)
    x0 += ks0; x1 += ks1 + 3u;
    TFR(17) TFR(29) TFR(16) TFR(24)
    x0 += ks1; x1 += ks2 + 4u;
    TFR(13) TFR(15) TFR(26) TFR(6)
    x0 += ks2; x1 += ks0 + 5u;
#undef TFR
}

// ---------------------------------------------------------------------------
// logits = q . k, legal softmax, gumbel-argmax sample.
// Uniform bits follow JAX's PARTITIONABLE threefry (modern default,
// jax_threefry_partitionable=True): per-element 64-bit counter i, block
// inputs (hi32(i), lo32(i)) = (0, i), 32-bit output word = y0 ^ y1.
// Race values in f64 (error ~3e-7, far below certified top-2 gumbel gaps).
// 1 thread per (slot, move); groups of 4 lanes cooperate via shfl_xor.
// ---------------------------------------------------------------------------
__global__ __launch_bounds__(256)
void logits_sample_kernel(const float* __restrict__ Q, const float* __restrict__ Kv,
                          const int* __restrict__ mask,
                          float* __restrict__ out_logits, float* __restrict__ out_policy,
                          float* __restrict__ out_index)
{
    const int t    = blockIdx.x * 256 + threadIdx.x;  // 0 .. RM_-1
    const int slot = t >> 2;
    const int m    = t & 3;

    const float4* qp = (const float4*)&Q[(size_t)slot * F4_];
    const float4* kp = (const float4*)&Kv[(size_t)t * F4_];
    double dot = 0.0;
#pragma unroll
    for (int i = 0; i < 32; i++) {
        float4 a = qp[i], b = kp[i];
        dot += (double)a.x * b.x; dot += (double)a.y * b.y;
        dot += (double)a.z * b.z; dot += (double)a.w * b.w;
    }

    const bool legal = (mask[t] != 0);

    // min over all 4 logits
    double lmin = fmin(dot, __shfl_xor(dot, 1));
    lmin = fmin(lmin, __shfl_xor(lmin, 2));
    // masked logits, max over them
    const double lm = legal ? dot : lmin;
    double lmax = fmax(lm, __shfl_xor(lm, 1));
    lmax = fmax(lmax, __shfl_xor(lmax, 2));
    // exp / normalize (f64)
    const double e = legal ? exp(lm - lmax) : 0.0;
    double esum = e + __shfl_xor(e, 1);
    esum += __shfl_xor(esum, 2);
    const double policy = e / esum;

    out_logits[t] = (float)dot;
    out_policy[t] = (float)policy;

    // sampling logits (log-policy; illegal -> -1e30), f64
    const double sl = (policy > 0.0) ? log(policy) : -1e30;

    // Partitionable threefry bits: counter = t (u64) -> block (0, t), word = y0^y1
    unsigned int x0 = 0u;
    unsigned int x1 = (unsigned int)t;
    threefry2x32_k42(x0, x1);
    const unsigned int bits = x0 ^ x1;

    // bit-identical fp32 uniform, then exact f64 gumbel transform
    const float f  = __uint_as_float(0x3f800000u | (bits >> 9)) - 1.0f;
    const float uf = fmaxf(1.17549435e-38f, f);
    const double g = -log(-log((double)uf));
    const double v = sl + g;

    // argmax over 4 lanes, lowest index wins ties (jnp.argmax semantics)
    int    best = m;
    double bv   = v;
    {
        double ov = __shfl_xor(bv, 1); int oi = __shfl_xor(best, 1);
        if (ov > bv || (ov == bv && oi < best)) { bv = ov; best = oi; }
        ov = __shfl_xor(bv, 2); oi = __shfl_xor(best, 2);
        if (ov > bv || (ov == bv && oi < best)) { bv = ov; best = oi; }
    }
    if (m == 0) out_index[slot] = (float)best;
}

// ---------------------------------------------------------------------------
// gather sampled move row, project (256 -> 512), fuse ar_out epilogue
// 32 rows x 128 cols per block
// ---------------------------------------------------------------------------
__global__ __launch_bounds__(256, 3)
void proj_kernel(const float* __restrict__ moves, const float* __restrict__ idxf,
                 const float* __restrict__ Wp, const float* __restrict__ bp,
                 const float* __restrict__ x, const int* __restrict__ atype,
                 float* __restrict__ out_ar, float* __restrict__ out_proj)
{
    __shared__ float As[32][260];
    __shared__ float Bs[32 * 128];

    const int tid  = threadIdx.x;
    const int row0 = blockIdx.x * 32;
    const int col0 = blockIdx.y * 128;
    const int tx   = tid & 31;
    const int ty   = tid >> 5;

    // gather 32 sampled move rows (256 floats each)
#pragma unroll
    for (int it = 0; it < 8; it++) {
        int r = (tid >> 6) + it * 4;
        int c = (tid & 63) * 4;
        int slot = row0 + r;
        int mi = (int)idxf[slot];
        float4 v = *(const float4*)&moves[((size_t)slot * 4 + mi) * F2_ + c];
        *(float4*)&As[r][c] = v;
    }
    __syncthreads();

    float acc[4][4];
#pragma unroll
    for (int i = 0; i < 4; i++)
#pragma unroll
        for (int j = 0; j < 4; j++) acc[i][j] = 0.f;

    for (int k0 = 0; k0 < F2_; k0 += 32) {
        {   // Wp chunk: 32 k x 128 n
            int kk = tid >> 3;
            int c0 = (tid & 7) * 16;
            const float* src = &Wp[(size_t)(k0 + kk) * F_ + col0 + c0];
            float* dst = &Bs[kk * 128 + c0];
#pragma unroll
            for (int j = 0; j < 4; j++) ((float4*)dst)[j] = ((const float4*)src)[j];
        }
        __syncthreads();
#pragma unroll
        for (int kk = 0; kk < 32; kk += 4) {
            float4 h[4];
#pragma unroll
            for (int i = 0; i < 4; i++) h[i] = *(const float4*)&As[ty * 4 + i][k0 + kk];
#pragma unroll
            for (int u = 0; u < 4; u++) {
                float4 w = *(const float4*)&Bs[(kk + u) * 128 + tx * 4];
#pragma unroll
                for (int i = 0; i < 4; i++) {
                    float hv = ((const float*)&h[i])[u];
                    acc[i][0] += hv * w.x; acc[i][1] += hv * w.y;
                    acc[i][2] += hv * w.z; acc[i][3] += hv * w.w;
                }
            }
        }
        __syncthreads();
    }

    float4 bb = *(const float4*)&bp[col0 + tx * 4];
#pragma unroll
    for (int i = 0; i < 4; i++) {
        int row = row0 + ty * 4 + i;
        float4 p;
        p.x = acc[i][0] + bb.x;
        p.y = acc[i][1] + bb.y;
        p.z = acc[i][2] + bb.z;
        p.w = acc[i][3] + bb.w;
        size_t off = (size_t)row * F_ + col0 + tx * 4;
        *(float4*)&out_proj[off] = p;
        float4 a = *(const float4*)&x[off];
        bool valid = (atype[row] == 0);
        float4 r4;
        r4.x = valid ? a.x + p.x : a.x;
        r4.y = valid ? a.y + p.y : a.y;
        r4.z = valid ? a.z + p.z : a.z;
        r4.w = valid ? a.w + p.w : a.w;
        *(float4*)&out_ar[off] = r4;
    }
}

// ---------------------------------------------------------------------------
extern "C" void kernel_launch(void* const* d_in, const int* in_sizes, int n_in,
                              void* d_out, int out_size, void* d_ws, size_t ws_size,
                              hipStream_t stream)
{
    (void)in_sizes; (void)n_in; (void)out_size; (void)d_ws; (void)ws_size;

    const int*   atype = (const int*)d_in[0];
    const float* x     = (const float*)d_in[1];
    const float* moves = (const float*)d_in[2];
    const int*   mask  = (const int*)d_in[3];
    const float* Wq1   = (const float*)d_in[4];
    const float* bq1   = (const float*)d_in[5];
    const float* Wq2   = (const float*)d_in[6];
    const float* bq2   = (const float*)d_in[7];
    const float* Wk1   = (const float*)d_in[8];
    const float* bk1   = (const float*)d_in[9];
    const float* Wk2   = (const float*)d_in[10];
    const float* bk2   = (const float*)d_in[11];
    const float* Wp    = (const float*)d_in[12];
    const float* bp    = (const float*)d_in[13];

    float* out_logits = (float*)d_out;                   // [R_,4]
    float* out_policy = out_logits + RM_;                // [R_,4]
    float* out_index  = out_policy + RM_;                // [R_,1]
    float* out_ar     = out_index + R_;                  // [R_,512]
    float* out_proj   = out_ar + (size_t)R_ * F_;        // [R_,512]

    // Scratch inside d_out regions that are overwritten later:
    //   Q  (16 MB) -> out_proj region; Kv (64 MB) -> out_ar region (exact fit)
    float* Q  = out_proj;
    float* Kv = out_ar;

    mlp2_kernel<F_><<<R_ / 32, 256, 0, stream>>>(x, Wq1, bq1, Wq2, bq2, Q);
    mlp2_kernel<F2_><<<RM_ / 32, 256, 0, stream>>>(moves, Wk1, bk1, Wk2, bk2, Kv);
    logits_sample_kernel<<<RM_ / 256, 256, 0, stream>>>(Q, Kv, mask,
                                                        out_logits, out_policy, out_index);
    dim3 pgrid(R_ / 32, 4);
    proj_kernel<<<pgrid, 256, 0, stream>>>(moves, out_index, Wp, bp, x, atype,
                                           out_ar, out_proj);
}